// Round 7
// baseline (545.815 us; speedup 1.0000x reference)
//
#include <hip/hip_runtime.h>
#include <hip/hip_cooperative_groups.h>
#include <hip/hip_bf16.h>
#include <stdint.h>

namespace cg = cooperative_groups;

// Problem: x[128,64,1024] fp32; W1,W2 [1024,1024] fp32 (torch Linear, y = x @ W^T)
//   h = x @ W1^T ; spikes = LIF_scan(h) ; out = spikes @ W2^T  (spike rate ~0.1-0.2%)
//
// GEMM1 via f16 2-split on MFMA: a = a0 + a1/4096 (+ r ~ 2^-22|a|),
//   A.B^T ~= A0B0 + (A0B1s + A1sB0)/4096
// Round 7: ONE cooperative kernel (prep -> gemm -> scan -> spmm with grid.sync) to kill
// ~12-15us/dispatch graph-replay gaps (cross-round evidence). Gemm = round-5 body (prep-split
// A, 69us proven, 0 LDS conflicts) + XCD remap (round-6, FETCH 133->33MB). Fallback to 4
// separate kernels if hipLaunchCooperativeKernel errors. All arithmetic bitwise-identical.
// ws (needs 43 MiB, proven r3-r5): [0,1M) masks | [1,5M) W2T | [5M) A0 | [22M) A1 | [39M) B0 | [41M) B1

#define TT 128
#define BB 64
#define NN 1024
#define MROWS (TT * BB)          // 8192
#define SROW  (BB * NN)          // 65536
#define MiB   ((size_t)1048576)

typedef _Float16 h8  __attribute__((ext_vector_type(8)));
typedef _Float16 h4v __attribute__((ext_vector_type(4)));
typedef float    f4  __attribute__((ext_vector_type(4)));

#define GL2LDS(g, l) __builtin_amdgcn_global_load_lds(                         \
    (const __attribute__((address_space(1))) void*)(const void*)(g),           \
    (__attribute__((address_space(3))) void*)(void*)(l), 16, 0, 0)

// ---------------- phase bodies (shared by fused + fallback kernels) -------------------------

__device__ __forceinline__ void dev_split4(const float* __restrict__ src,
                                           _Float16* __restrict__ d0,
                                           _Float16* __restrict__ d1, int i) {
    const float4 v = reinterpret_cast<const float4*>(src)[i];
    const float f[4] = {v.x, v.y, v.z, v.w};
    h4v a0, a1;
#pragma unroll
    for (int j = 0; j < 4; ++j) {
        const _Float16 c = (_Float16)f[j];
        a0[j] = c;
        a1[j] = (_Float16)((f[j] - (float)c) * 4096.0f);  // scaled: no f16 subnormals
    }
    reinterpret_cast<h4v*>(d0)[i] = a0;
    reinterpret_cast<h4v*>(d1)[i] = a1;
}

__device__ __forceinline__ void dev_transpose(int tIdx, int tid, const float* __restrict__ in,
                                              float* __restrict__ outp, float* tile /*32x33*/) {
    const int bx = (tIdx & 31) * 32, by = (tIdx >> 5) * 32;
    const int tx = tid & 31, ty = tid >> 5;          // 32 x 8
#pragma unroll
    for (int j = 0; j < 32; j += 8)
        tile[(ty + j) * 33 + tx] = in[(size_t)(by + ty + j) * NN + bx + tx];
    __syncthreads();
#pragma unroll
    for (int j = 0; j < 32; j += 8)
        outp[(size_t)(bx + ty + j) * NN + by + tx] = tile[tx * 33 + ty + j];
    __syncthreads();   // tile reused next iteration in fused loop
}

// round-5 proven gemm body (f16 A0/A1 staged; both-sides chunk swizzle; 0 bank conflicts)
// + XCD remap: ib bits [8:6]=q, [5:3]=col, [2:0]=xcd -> panel p=q*8+xcd shares one XCD's L2.
__device__ __forceinline__ void dev_gemm(int ib, int tid, unsigned char* smem,
                                         const _Float16* __restrict__ A0,
                                         const _Float16* __restrict__ A1,
                                         const _Float16* __restrict__ B0,
                                         const _Float16* __restrict__ B1,
                                         float* __restrict__ C) {
    _Float16* As0 = (_Float16*)smem;               // [2][4096]
    _Float16* As1 = (_Float16*)(smem + 16384);
    _Float16* Bs0 = (_Float16*)(smem + 32768);
    _Float16* Bs1 = (_Float16*)(smem + 49152);
    const int lane = tid & 63, wid = tid >> 6;
    const int wr = wid >> 1, wc = wid & 1;
    const int p  = ((ib >> 6) << 3) + (ib & 7);    // A row-panel 0..63
    const int cc = (ib >> 3) & 7;                  // col tile 0..7
    const int rowBase = p * 128, colBase = cc * 128;

    // staging: wave w covers rows [w*32,+32) as 2 insts of 16 rows (1KB each);
    // lane l -> row +(l>>2), phys slot l&3, global chunk (l&3)^((row>>1)&3)
    const int srow = wid * 32 + (lane >> 2);
    const int swz  = (((lane & 3) ^ ((srow >> 1) & 3)) << 3);
    const size_t aOff0 = (size_t)(rowBase + srow) * NN + swz;
    const size_t aOff1 = aOff0 + (size_t)16 * NN;  // rows r,r+16 share (r>>1)&3 parity (bit4)
    const size_t bOff0 = (size_t)(colBase + srow) * NN + swz;
    const size_t bOff1 = bOff0 + (size_t)16 * NN;
    const int l0 = wid * 1024, l1 = wid * 1024 + 512;

    int fA[4], fB[4];
#pragma unroll
    for (int i = 0; i < 4; ++i) {
        const int ra = wr * 64 + i * 16 + (lane & 15);
        const int rb = wc * 64 + i * 16 + (lane & 15);
        fA[i] = ra * 32 + (((lane >> 4) ^ ((ra >> 1) & 3)) << 3);
        fB[i] = rb * 32 + (((lane >> 4) ^ ((rb >> 1) & 3)) << 3);
    }

    f4 acc0[4][4], acc1[4][4];
#pragma unroll
    for (int i = 0; i < 4; ++i)
#pragma unroll
        for (int j = 0; j < 4; ++j) { acc0[i][j] = (f4)0.0f; acc1[i][j] = (f4)0.0f; }

#define STAGE(bi, K0)                                            \
    do {                                                         \
        GL2LDS(A0 + aOff0 + (K0), &As0[(bi) * 4096 + l0]);       \
        GL2LDS(A0 + aOff1 + (K0), &As0[(bi) * 4096 + l1]);       \
        GL2LDS(A1 + aOff0 + (K0), &As1[(bi) * 4096 + l0]);       \
        GL2LDS(A1 + aOff1 + (K0), &As1[(bi) * 4096 + l1]);       \
        GL2LDS(B0 + bOff0 + (K0), &Bs0[(bi) * 4096 + l0]);       \
        GL2LDS(B0 + bOff1 + (K0), &Bs0[(bi) * 4096 + l1]);       \
        GL2LDS(B1 + bOff0 + (K0), &Bs1[(bi) * 4096 + l0]);       \
        GL2LDS(B1 + bOff1 + (K0), &Bs1[(bi) * 4096 + l1]);       \
    } while (0)

    STAGE(0, 0);
    __syncthreads();

    for (int t = 0; t < 32; ++t) {
        const int cur = t & 1;
        if (t < 31) STAGE(cur ^ 1, (t + 1) * 32);   // issue next-tile loads before compute
        h8 a0f[4], a1f[4], b0f[4], b1f[4];
#pragma unroll
        for (int i = 0; i < 4; ++i) {
            a0f[i] = *(const h8*)&As0[cur * 4096 + fA[i]];
            a1f[i] = *(const h8*)&As1[cur * 4096 + fA[i]];
            b0f[i] = *(const h8*)&Bs0[cur * 4096 + fB[i]];
            b1f[i] = *(const h8*)&Bs1[cur * 4096 + fB[i]];
        }
#pragma unroll
        for (int i = 0; i < 4; ++i)
#pragma unroll
            for (int j = 0; j < 4; ++j) {
                acc0[i][j] = __builtin_amdgcn_mfma_f32_16x16x32_f16(a0f[i], b0f[j], acc0[i][j], 0, 0, 0);
                acc1[i][j] = __builtin_amdgcn_mfma_f32_16x16x32_f16(a0f[i], b1f[j], acc1[i][j], 0, 0, 0);
                acc1[i][j] = __builtin_amdgcn_mfma_f32_16x16x32_f16(a1f[i], b0f[j], acc1[i][j], 0, 0, 0);
            }
        __syncthreads();
    }
#undef STAGE

    // C/D layout (m89-verified): col = lane&15, row = (lane>>4)*4 + reg
    const int orow = rowBase + wr * 64 + (lane >> 4) * 4;
    const int ocol = colBase + wc * 64 + (lane & 15);
#pragma unroll
    for (int i = 0; i < 4; ++i)
#pragma unroll
        for (int j = 0; j < 4; ++j)
#pragma unroll
            for (int q = 0; q < 4; ++q)
                C[(size_t)(orow + i * 16 + q) * NN + ocol + j * 16] =
                    acc0[i][j][q] + acc1[i][j][q] * (1.0f / 4096.0f);
}

// LIF scan chain for one (b,n): exact reference arithmetic; 16-deep prefetch.
__device__ __forceinline__ void dev_scan(int c, const float* __restrict__ H,
                                         unsigned long long* __restrict__ mask, int tid) {
    const int b = c >> 10, n = c & 1023, word = n >> 6;
    const bool lane0 = (tid & 63) == 0;
    float v = 0.0f;
    float buf[16];
#pragma unroll
    for (int j = 0; j < 16; ++j) buf[j] = H[(size_t)j * SROW + c];
    for (int t0 = 0; t0 < TT; t0 += 16) {
        float nbuf[16];
        if (t0 + 16 < TT) {
#pragma unroll
            for (int j = 0; j < 16; ++j) nbuf[j] = H[(size_t)(t0 + 16 + j) * SROW + c];
        } else {
#pragma unroll
            for (int j = 0; j < 16; ++j) nbuf[j] = 0.f;
        }
#pragma unroll
        for (int j = 0; j < 16; ++j) {
            const float x = buf[j];
            const float h = v + (x - v) * 0.5f;
            const bool s = (h >= 1.0f);
            v = s ? 0.0f : h;
            const unsigned long long m = __ballot(s);
            if (lane0) mask[((size_t)(t0 + j) * BB + b) * 16 + word] = m;
        }
#pragma unroll
        for (int j = 0; j < 16; ++j) buf[j] = nbuf[j];
    }
}

// sparse GEMM2 for 16 rows: out[r,:] = sum_{n: spike} W2T[n,:]; masks cached in LDS once.
__device__ __forceinline__ void dev_spmm16(int blk, int tid,
                                           const unsigned long long* __restrict__ mask,
                                           const float* __restrict__ W2T,
                                           float* __restrict__ outp,
                                           unsigned long long* sw /*LDS 256 u64*/) {
    sw[tid] = mask[(size_t)blk * 256 + tid];
    __syncthreads();
#pragma unroll 1
    for (int rr = 0; rr < 16; ++rr) {
        const int r = blk * 16 + rr;
        f4 acc = (f4)0.0f;
#pragma unroll 1
        for (int w = 0; w < 16; ++w) {
            unsigned long long bits = sw[rr * 16 + w];
            while (bits) {
                const int n2 = w * 64 + (__ffsll(bits) - 1);
                bits &= bits - 1;
                const f4 rv = reinterpret_cast<const f4*>(W2T + (size_t)n2 * NN)[tid];
                acc[0] += rv[0]; acc[1] += rv[1]; acc[2] += rv[2]; acc[3] += rv[3];
            }
        }
        reinterpret_cast<f4*>(outp + (size_t)r * NN)[tid] = acc;
    }
}

// ---------------- fused cooperative kernel ---------------------------------------------------
__global__ __launch_bounds__(256, 2) void fused(const float* __restrict__ x,
                                                const float* __restrict__ W1,
                                                const float* __restrict__ W2,
                                                float* __restrict__ out,
                                                unsigned long long* __restrict__ mask,
                                                _Float16* __restrict__ A0, _Float16* __restrict__ A1,
                                                _Float16* __restrict__ B0, _Float16* __restrict__ B1,
                                                float* __restrict__ W2T) {
    __shared__ __align__(16) unsigned char smem[65536];
    const int tid = threadIdx.x, blk = blockIdx.x;
    cg::grid_group grid = cg::this_grid();

    // phase 0: prep — 10240 virtual blocks over 512 real (20 each)
#pragma unroll 1
    for (int it = 0; it < 20; ++it) {
        const int vb = blk * 20 + it;
        if (vb < 8192)       dev_split4(x, A0, A1, vb * 256 + tid);
        else if (vb < 9216)  dev_split4(W1, B0, B1, (vb - 8192) * 256 + tid);
        else                 dev_transpose(vb - 9216, tid, W2, W2T, (float*)smem);
    }
    __threadfence();
    grid.sync();

    // phase 1: H = x @ W1^T  (stored in d_out as scratch)
    dev_gemm(blk, tid, smem, A0, A1, B0, B1, out);
    __threadfence();
    grid.sync();

    // phase 2: LIF scan -> spike bitmasks (65536 chains spread over all blocks)
    if (tid < 128) dev_scan(blk * 128 + tid, out, mask, tid);
    __threadfence();
    grid.sync();

    // phase 3: out = spikes @ W2^T
    dev_spmm16(blk, tid, mask, W2T, out, (unsigned long long*)smem);
}

// ---------------- fallback separate kernels (same device bodies, same math) ------------------
__global__ __launch_bounds__(256) void k_prep(const float* __restrict__ x,
                                              const float* __restrict__ W1,
                                              const float* __restrict__ W2,
                                              _Float16* __restrict__ A0, _Float16* __restrict__ A1,
                                              _Float16* __restrict__ B0, _Float16* __restrict__ B1,
                                              float* __restrict__ W2T) {
    __shared__ float tile[32 * 33];
    const int vb = blockIdx.x, tid = threadIdx.x;
    if (vb < 8192)       dev_split4(x, A0, A1, vb * 256 + tid);
    else if (vb < 9216)  dev_split4(W1, B0, B1, (vb - 8192) * 256 + tid);
    else                 dev_transpose(vb - 9216, tid, W2, W2T, tile);
}

__global__ __launch_bounds__(256, 2) void k_gemm(const _Float16* __restrict__ A0,
                                                 const _Float16* __restrict__ A1,
                                                 const _Float16* __restrict__ B0,
                                                 const _Float16* __restrict__ B1,
                                                 float* __restrict__ C) {
    __shared__ __align__(16) unsigned char smem[65536];
    dev_gemm(blockIdx.x, threadIdx.x, smem, A0, A1, B0, B1, C);
}

__global__ __launch_bounds__(256) void k_scan(const float* __restrict__ H,
                                              unsigned long long* __restrict__ mask) {
    if (threadIdx.x < 128) dev_scan(blockIdx.x * 128 + threadIdx.x, H, mask, threadIdx.x);
}

__global__ __launch_bounds__(256) void k_spmm(const unsigned long long* __restrict__ mask,
                                              const float* __restrict__ W2T,
                                              float* __restrict__ outp) {
    __shared__ unsigned long long sw[256];
    dev_spmm16(blockIdx.x, threadIdx.x, mask, W2T, outp, sw);
}

extern "C" void kernel_launch(void* const* d_in, const int* in_sizes, int n_in,
                              void* d_out, int out_size, void* d_ws, size_t ws_size,
                              hipStream_t stream) {
    const float* x  = (const float*)d_in[0];
    const float* W1 = (const float*)d_in[1];
    const float* W2 = (const float*)d_in[2];
    float* out = (float*)d_out;

    unsigned long long* mask = (unsigned long long*)d_ws;
    float* W2T   = (float*)((char*)d_ws + 1 * MiB);
    _Float16* A0 = (_Float16*)((char*)d_ws + 5 * MiB);
    _Float16* A1 = (_Float16*)((char*)d_ws + 22 * MiB);
    _Float16* B0 = (_Float16*)((char*)d_ws + 39 * MiB);
    _Float16* B1 = (_Float16*)((char*)d_ws + 41 * MiB);

    void* kargs[] = {(void*)&x, (void*)&W1, (void*)&W2, (void*)&out, (void*)&mask,
                     (void*)&A0, (void*)&A1, (void*)&B0, (void*)&B1, (void*)&W2T};
    hipError_t err = hipLaunchCooperativeKernel((void*)fused, dim3(512), dim3(256),
                                                kargs, 0, stream);
    if (err != hipSuccess) {
        // deterministic fallback: same device bodies as 4 separate dispatches
        k_prep<<<10240, 256, 0, stream>>>(x, W1, W2, A0, A1, B0, B1, W2T);
        k_gemm<<<512, 256, 0, stream>>>(A0, A1, B0, B1, out);
        k_scan<<<512, 256, 0, stream>>>(out, mask);
        k_spmm<<<512, 256, 0, stream>>>(mask, W2T, out);
    }
}

// Round 8
// 164.153 us; speedup vs baseline: 3.3250x; 3.3250x over previous
//
#include <hip/hip_runtime.h>
#include <hip/hip_bf16.h>
#include <stdint.h>

// Problem: x[128,64,1024] fp32; W1,W2 [1024,1024] fp32 (torch Linear, y = x @ W^T)
//   h = x @ W1^T ; spikes = LIF_scan(h) ; out = spikes @ W2^T  (spike rate ~0.1-0.2%)
//
// GEMM1 via f16 2-split on MFMA: a = a0 + a1/4096 (+ r ~ 2^-22|a|),
//   A.B^T ~= A0B0 + (A0B1s + A1sB0)/4096
// Round 8: back to 4 dispatches (r7 cooperative fusion = 476us: grid.sync + threadfence
// across 8 XCDs >> graph-replay gaps). Gemm: A-split in the STAGING path (T14 issue-early/
// write-late reg-staging: fp32 x -> regs at phase start, cvt+ds_write after MFMA cluster) —
// keeps r5's clean ds_read->MFMA critical path (69us, 0 conflicts) AND r6's no-prep-A /
// FETCH=33MB wins. B via global_load_lds with pre-swizzled source (r5-proven).
// ws: [0,1M) masks | [1,5M) W2T | [5M) B0 2M | [7M) B1 2M  (needs 9 MiB; else fp32 fallback)

#define TT 128
#define BB 64
#define NN 1024
#define MROWS (TT * BB)          // 8192
#define SROW  (BB * NN)          // 65536
#define MiB   ((size_t)1048576)

typedef _Float16 h8  __attribute__((ext_vector_type(8)));
typedef _Float16 h4v __attribute__((ext_vector_type(4)));
typedef float    f4  __attribute__((ext_vector_type(4)));
typedef float    v2f __attribute__((ext_vector_type(2)));

#if __has_builtin(__builtin_elementwise_fma)
#define V2FMA(a, b, c) __builtin_elementwise_fma((a), (b), (c))
#else
static __device__ __forceinline__ v2f v2fma_(v2f a, v2f b, v2f c) {
    v2f r; r[0] = fmaf(a[0], b[0], c[0]); r[1] = fmaf(a[1], b[1], c[1]); return r;
}
#define V2FMA(a, b, c) v2fma_((a), (b), (c))
#endif

#define GL2LDS(g, l) __builtin_amdgcn_global_load_lds(                         \
    (const __attribute__((address_space(1))) void*)(const void*)(g),           \
    (__attribute__((address_space(3))) void*)(void*)(l), 16, 0, 0)

// ---------------- prep: split W1, transpose W2 ----------------------------------------------
__global__ __launch_bounds__(256) void prep(const float* __restrict__ W1,
                                            const float* __restrict__ W2,
                                            _Float16* __restrict__ B0, _Float16* __restrict__ B1,
                                            float* __restrict__ W2T) {
    const int nb = blockIdx.x;
    const int tid = threadIdx.x;
    if (nb < 1024) {
        const int i = nb * 256 + tid;
        const float4 v = reinterpret_cast<const float4*>(W1)[i];
        const float f[4] = {v.x, v.y, v.z, v.w};
        h4v a0, a1;
#pragma unroll
        for (int j = 0; j < 4; ++j) {
            const _Float16 c = (_Float16)f[j];
            a0[j] = c;
            a1[j] = (_Float16)((f[j] - (float)c) * 4096.0f);  // scaled: no f16 subnormals
        }
        reinterpret_cast<h4v*>(B0)[i] = a0;
        reinterpret_cast<h4v*>(B1)[i] = a1;
    } else {
        __shared__ float tile[32][33];
        const int tIdx = nb - 1024;
        const int bx = (tIdx & 31) * 32, by = (tIdx >> 5) * 32;
        const int tx = tid & 31, ty = tid >> 5;          // 32 x 8
#pragma unroll
        for (int j = 0; j < 32; j += 8)
            tile[ty + j][tx] = W2[(size_t)(by + ty + j) * NN + bx + tx];
        __syncthreads();
#pragma unroll
        for (int j = 0; j < 32; j += 8)
            W2T[(size_t)(bx + ty + j) * NN + by + tx] = tile[tx][ty + j];
    }
}

// ---------------- MFMA GEMM: C[8192,1024] f32, merged 3-product K-loop ----------------------
// 128x128 tile, 4 waves (2x2), 16x16x32 f16 MFMA, K_STEP=32, double-buffered LDS.
// A: reg-staged from raw fp32 x (T14): loads issued at phase start, cvt-to-(f16,f16*4096)
//    + swizzled ds_write_b128 AFTER the MFMA cluster -> split off the critical path.
// B: global_load_lds, pre-swizzled source (r5 pattern, 0 conflicts).
// LDS layout both: [row][k] f16, 64B rows = 4x16B chunks, phys chunk = logical ^ ((row>>1)&3).
// XCD remap: ib -> panel p=(ib>>6)*8+(ib&7), col cc=(ib>>3)&7 (panel's col-tiles share an XCD L2).
__global__ __launch_bounds__(256, 2) void gemm_rs(const float* __restrict__ X,
                                                  const _Float16* __restrict__ B0g,
                                                  const _Float16* __restrict__ B1g,
                                                  float* __restrict__ C) {
    __shared__ _Float16 As0[2][4096], As1[2][4096];
    __shared__ _Float16 Bs0[2][4096], Bs1[2][4096];
    const int tid = threadIdx.x, lane = tid & 63, wid = tid >> 6;
    const int wr = wid >> 1, wc = wid & 1;
    const int ib = blockIdx.x;
    const int p  = ((ib >> 6) << 3) + (ib & 7);
    const int cc = (ib >> 3) & 7;
    const int rowBase = p * 128, colBase = cc * 128;

    // A reg-staging: iter i in {0,1}: row r = wid*32 + i*16 + (lane>>2), f16-chunk c = lane&3
    // (covers k in [8c, 8c+8) = 32B of fp32 x = two dwordx4 loads).
    const int sr = wid * 32 + (lane >> 2);
    const int sc = lane & 3;
    const size_t xOff = (size_t)(rowBase + sr) * NN + sc * 8;
    const int wsw = (sc ^ ((sr >> 1) & 3)) << 3;          // rows r, r+16 share (r>>1)&3 (bit4 only)
    const int wA0 = sr * 32 + wsw;                        // f16-elem LDS offsets
    const int wA1 = (sr + 16) * 32 + wsw;

    // B staging (global_load_lds, source pre-swizzled)
    const int swzB = (((lane & 3) ^ ((sr >> 1) & 3)) << 3);
    const size_t bOff0 = (size_t)(colBase + sr) * NN + swzB;
    const size_t bOff1 = bOff0 + (size_t)16 * NN;
    const int l0 = wid * 1024, l1 = l0 + 512;

    // fragment read addrs: row, logical chunk = lane>>4, phys = logical ^ ((row>>1)&3)
    int fA[4], fB[4];
#pragma unroll
    for (int i = 0; i < 4; ++i) {
        const int ra = wr * 64 + i * 16 + (lane & 15);
        const int rb = wc * 64 + i * 16 + (lane & 15);
        fA[i] = ra * 32 + (((lane >> 4) ^ ((ra >> 1) & 3)) << 3);
        fB[i] = rb * 32 + (((lane >> 4) ^ ((rb >> 1) & 3)) << 3);
    }

    f4 acc0[4][4], acc1[4][4];
#pragma unroll
    for (int i = 0; i < 4; ++i)
#pragma unroll
        for (int j = 0; j < 4; ++j) { acc0[i][j] = (f4)0.0f; acc1[i][j] = (f4)0.0f; }

    f4 xa0, xa1, xb0, xb1;   // staged x: iter0 floats k[8c..8c+8), iter1 same rows+16

#define XLOAD(K0)                                              \
    do {                                                       \
        const size_t xo = xOff + (K0);                         \
        xa0 = *(const f4*)(X + xo);                            \
        xa1 = *(const f4*)(X + xo + 4);                        \
        xb0 = *(const f4*)(X + xo + (size_t)16 * NN);          \
        xb1 = *(const f4*)(X + xo + (size_t)16 * NN + 4);      \
    } while (0)

#define BSTAGE(bi, K0)                                         \
    do {                                                       \
        GL2LDS(B0g + bOff0 + (K0), &Bs0[bi][l0]);              \
        GL2LDS(B0g + bOff1 + (K0), &Bs0[bi][l1]);              \
        GL2LDS(B1g + bOff0 + (K0), &Bs1[bi][l0]);              \
        GL2LDS(B1g + bOff1 + (K0), &Bs1[bi][l1]);              \
    } while (0)

    // cvt + swizzled write of the staged x into buffer bi (bitwise-identical split math)
#define AWRITE(bi)                                                             \
    do {                                                                       \
        h8 hi, lo;                                                             \
        _Pragma("unroll") for (int e = 0; e < 4; ++e) {                        \
            const float f0 = xa0[e], f1 = xa1[e];                              \
            const _Float16 c0 = (_Float16)f0, c1 = (_Float16)f1;               \
            hi[e] = c0; hi[4 + e] = c1;                                        \
            lo[e]     = (_Float16)((f0 - (float)c0) * 4096.0f);                \
            lo[4 + e] = (_Float16)((f1 - (float)c1) * 4096.0f);                \
        }                                                                      \
        *(h8*)&As0[bi][wA0] = hi; *(h8*)&As1[bi][wA0] = lo;                    \
        _Pragma("unroll") for (int e = 0; e < 4; ++e) {                        \
            const float f0 = xb0[e], f1 = xb1[e];                              \
            const _Float16 c0 = (_Float16)f0, c1 = (_Float16)f1;               \
            hi[e] = c0; hi[4 + e] = c1;                                        \
            lo[e]     = (_Float16)((f0 - (float)c0) * 4096.0f);                \
            lo[4 + e] = (_Float16)((f1 - (float)c1) * 4096.0f);                \
        }                                                                      \
        *(h8*)&As0[bi][wA1] = hi; *(h8*)&As1[bi][wA1] = lo;                    \
    } while (0)

    // prologue: tile 0
    XLOAD(0);
    BSTAGE(0, 0);
    AWRITE(0);
    __syncthreads();

    for (int t = 0; t < 32; ++t) {
        const int cur = t & 1;
        if (t < 31) {                    // issue next-tile loads EARLY (latency under MFMA)
            XLOAD((t + 1) * 32);
            BSTAGE(cur ^ 1, (t + 1) * 32);
        }
        h8 a0f[4], a1f[4], b0f[4], b1f[4];
#pragma unroll
        for (int i = 0; i < 4; ++i) {
            a0f[i] = *(const h8*)&As0[cur][fA[i]];
            a1f[i] = *(const h8*)&As1[cur][fA[i]];
            b0f[i] = *(const h8*)&Bs0[cur][fB[i]];
            b1f[i] = *(const h8*)&Bs1[cur][fB[i]];
        }
#pragma unroll
        for (int i = 0; i < 4; ++i)
#pragma unroll
            for (int j = 0; j < 4; ++j) {
                acc0[i][j] = __builtin_amdgcn_mfma_f32_16x16x32_f16(a0f[i], b0f[j], acc0[i][j], 0, 0, 0);
                acc1[i][j] = __builtin_amdgcn_mfma_f32_16x16x32_f16(a0f[i], b1f[j], acc1[i][j], 0, 0, 0);
                acc1[i][j] = __builtin_amdgcn_mfma_f32_16x16x32_f16(a1f[i], b0f[j], acc1[i][j], 0, 0, 0);
            }
        if (t < 31) AWRITE(cur ^ 1);     // write-late: cvt rides the post-MFMA shadow
        __syncthreads();
    }
#undef XLOAD
#undef BSTAGE
#undef AWRITE

    // C/D layout (m89-verified): col = lane&15, row = (lane>>4)*4 + reg
    const int orow = rowBase + wr * 64 + (lane >> 4) * 4;
    const int ocol = colBase + wc * 64 + (lane & 15);
#pragma unroll
    for (int i = 0; i < 4; ++i)
#pragma unroll
        for (int j = 0; j < 4; ++j)
#pragma unroll
            for (int q = 0; q < 4; ++q)
                C[(size_t)(orow + i * 16 + q) * NN + ocol + j * 16] =
                    acc0[i][j][q] + acc1[i][j][q] * (1.0f / 4096.0f);
}

// ---------------- LIF scan: H[t,b,n] -> spike bitmasks (exact reference arithmetic) ---------
__global__ __launch_bounds__(256) void lif_scan(const float* __restrict__ H,
                                                unsigned long long* __restrict__ mask) {
    const int g = blockIdx.x * 256 + threadIdx.x;
    const int b = g >> 10;
    const int n = g & 1023;
    const int word = n >> 6;
    const bool lane0 = (threadIdx.x & 63) == 0;

    float v = 0.0f;
    float buf[16];
#pragma unroll
    for (int j = 0; j < 16; ++j) buf[j] = H[(size_t)j * SROW + g];

    for (int t0 = 0; t0 < TT; t0 += 16) {
        float nbuf[16];
        if (t0 + 16 < TT) {
#pragma unroll
            for (int j = 0; j < 16; ++j) nbuf[j] = H[(size_t)(t0 + 16 + j) * SROW + g];
        } else {
#pragma unroll
            for (int j = 0; j < 16; ++j) nbuf[j] = 0.f;
        }
#pragma unroll
        for (int j = 0; j < 16; ++j) {
            const float x = buf[j];
            const float h = v + (x - v) * 0.5f;
            const bool s = (h >= 1.0f);
            v = s ? 0.0f : h;
            const unsigned long long m = __ballot(s);
            if (lane0) mask[((size_t)(t0 + j) * BB + b) * 16 + word] = m;
        }
#pragma unroll
        for (int j = 0; j < 16; ++j) buf[j] = nbuf[j];
    }
}

// ---------------- sparse GEMM2: out[r,:] = sum_{n: spike} W2T[n,:] ---------------------------
__global__ __launch_bounds__(256) void spike_matmul(const unsigned long long* __restrict__ mask,
                                                    const float* __restrict__ W2T,
                                                    float* __restrict__ out) {
    __shared__ unsigned long long sw[16];
    const int r = blockIdx.x;
    const int tid = threadIdx.x;
    if (tid < 16) sw[tid] = mask[(size_t)r * 16 + tid];
    __syncthreads();

    f4 acc = (f4)0.0f;
#pragma unroll 1
    for (int w = 0; w < 16; ++w) {
        unsigned long long bits = sw[w];
        while (bits) {
            const int n = w * 64 + (__ffsll(bits) - 1);
            bits &= bits - 1;
            const f4 rv = reinterpret_cast<const f4*>(W2T + (size_t)n * NN)[tid];
            acc[0] += rv[0]; acc[1] += rv[1]; acc[2] += rv[2]; acc[3] += rv[3];
        }
    }
    reinterpret_cast<f4*>(out + (size_t)r * NN)[tid] = acc;
}

// ---------------- W2 transpose (fallback path only) -----------------------------------------
__global__ __launch_bounds__(256) void transpose_nn(const float* __restrict__ in,
                                                    float* __restrict__ out) {
    __shared__ float tile[32][33];
    const int bx = blockIdx.x * 32, by = blockIdx.y * 32;
    const int tx = threadIdx.x, ty = threadIdx.y;
#pragma unroll
    for (int j = 0; j < 32; j += 8)
        tile[ty + j][tx] = in[(size_t)(by + ty + j) * NN + bx + tx];
    __syncthreads();
#pragma unroll
    for (int j = 0; j < 32; j += 8)
        out[(size_t)(bx + ty + j) * NN + by + tx] = tile[tx][ty + j];
}

// ---------------- fallback fp32 GEMM (used only if ws too small) -----------------------------
#define BM 128
#define BN 64
#define BK 16
__global__ __launch_bounds__(256, 4) void gemm1_f32(const float* __restrict__ A,
                                                    const float* __restrict__ B,
                                                    float* __restrict__ C) {
    __shared__ float Asb[2][BK][132];
    __shared__ float Bsb[2][BK][68];
    const int tid = threadIdx.x;
    const int ty = tid >> 4;
    const int tx = tid & 15;
    const int rowBase = blockIdx.y * BM;
    const int colBase = blockIdx.x * BN;
    const int sr = tid >> 2;
    const int sk = (tid & 3) * 4;

    const float* Ap0 = A + (size_t)(rowBase + sr) * NN + sk;
    const float* Ap1 = Ap0 + (size_t)64 * NN;
    const float* Bp  = B + (size_t)(colBase + sr) * NN + sk;

    v2f acc[4][4];
#pragma unroll
    for (int i = 0; i < 4; ++i)
#pragma unroll
        for (int j = 0; j < 4; ++j) acc[i][j] = (v2f){0.f, 0.f};

    float4 ra0 = *(const float4*)Ap0;
    float4 ra1 = *(const float4*)Ap1;
    float4 rb  = *(const float4*)Bp;

#define STW(buf)                                                                       \
    do {                                                                               \
        Asb[buf][sk + 0][sr] = ra0.x; Asb[buf][sk + 1][sr] = ra0.y;                    \
        Asb[buf][sk + 2][sr] = ra0.z; Asb[buf][sk + 3][sr] = ra0.w;                    \
        Asb[buf][sk + 0][sr + 64] = ra1.x; Asb[buf][sk + 1][sr + 64] = ra1.y;          \
        Asb[buf][sk + 2][sr + 64] = ra1.z; Asb[buf][sk + 3][sr + 64] = ra1.w;          \
        Bsb[buf][sk + 0][sr] = rb.x;  Bsb[buf][sk + 1][sr] = rb.y;                     \
        Bsb[buf][sk + 2][sr] = rb.z;  Bsb[buf][sk + 3][sr] = rb.w;                     \
    } while (0)

    STW(0);
    __syncthreads();
    const int NT = NN / BK;
    for (int t = 0; t < NT; ++t) {
        const int cur = t & 1;
        if (t < NT - 1) {
            const int ko = (t + 1) * BK;
            ra0 = *(const float4*)(Ap0 + ko);
            ra1 = *(const float4*)(Ap1 + ko);
            rb  = *(const float4*)(Bp + ko);
        }
#pragma unroll
        for (int k = 0; k < BK; ++k) {
            const v2f* ap = (const v2f*)&Asb[cur][k][ty * 8];
            const float4 bf = *(const float4*)&Bsb[cur][k][tx * 4];
            const float bb[4] = {bf.x, bf.y, bf.z, bf.w};
            const v2f a0 = ap[0], a1 = ap[1], a2 = ap[2], a3 = ap[3];
#pragma unroll
            for (int j = 0; j < 4; ++j) {
                const v2f bd = {bb[j], bb[j]};
                acc[0][j] = V2FMA(a0, bd, acc[0][j]);
                acc[1][j] = V2FMA(a1, bd, acc[1][j]);
                acc[2][j] = V2FMA(a2, bd, acc[2][j]);
                acc[3][j] = V2FMA(a3, bd, acc[3][j]);
            }
        }
        if (t < NT - 1) STW(cur ^ 1);
        __syncthreads();
    }
#undef STW
    float* Cp = C + (size_t)(rowBase + ty * 8) * NN + colBase + tx * 4;
#pragma unroll
    for (int rp = 0; rp < 4; ++rp) {
        float4 lo = {acc[rp][0][0], acc[rp][1][0], acc[rp][2][0], acc[rp][3][0]};
        float4 hi = {acc[rp][0][1], acc[rp][1][1], acc[rp][2][1], acc[rp][3][1]};
        *(float4*)(Cp + (size_t)(2 * rp) * NN)     = lo;
        *(float4*)(Cp + (size_t)(2 * rp + 1) * NN) = hi;
    }
}

extern "C" void kernel_launch(void* const* d_in, const int* in_sizes, int n_in,
                              void* d_out, int out_size, void* d_ws, size_t ws_size,
                              hipStream_t stream) {
    const float* x  = (const float*)d_in[0];
    const float* W1 = (const float*)d_in[1];
    const float* W2 = (const float*)d_in[2];
    float* out = (float*)d_out;

    unsigned long long* mask = (unsigned long long*)d_ws;
    float* W2T = (float*)((char*)d_ws + 1 * MiB);

    if (ws_size >= 9 * MiB) {
        _Float16* B0 = (_Float16*)((char*)d_ws + 5 * MiB);
        _Float16* B1 = (_Float16*)((char*)d_ws + 7 * MiB);

        prep<<<2048, 256, 0, stream>>>(W1, W2, B0, B1, W2T);
        gemm_rs<<<512, 256, 0, stream>>>(x, B0, B1, out);
    } else {
        transpose_nn<<<dim3(32, 32), dim3(32, 8), 0, stream>>>(W2, W2T);
        gemm1_f32<<<dim3(NN / BN, MROWS / BM), 256, 0, stream>>>(x, W1, out);
    }
    lif_scan<<<SROW / 256, 256, 0, stream>>>(out, mask);
    spike_matmul<<<MROWS, 256, 0, stream>>>(mask, W2T, out);
}